// Round 13
// baseline (1242.908 us; speedup 1.0000x reference)
//
#include <hip/hip_runtime.h>
#include <stdint.h>

// Problem constants (setup_inputs is fixed)
#define HH 192
#define WW 192
#define BB 8
#define NSTEP 10
#define HWSZ (HH*WW)    // 36864
#define NPIX (BB*HWSZ)  // 294912
#define TILE 16         // 16x16 pixel tile
#define XROWS 22        // TILE + 6 halo
#define XCOLS 22
#define RSU   360       // ushorts per LDS row (720B = 45*16B; dword stride 180 -> 2-way banks)
#define XBUFU (XROWS*RSU)   // 7920 ushorts per buffer (hi); lo at +XBUFU
#define NTAP  49        // K-steps: one 7x7 tap (16 ci) per step -> no padding
#define NBLK  (12*12*8) // conv1 grid = 1152 blocks

typedef _Float16 f16x8 __attribute__((ext_vector_type(8)));
typedef float    f32x16 __attribute__((ext_vector_type(16)));

union PackU { ushort u[8]; uint4 v; };

// ---------------- Threefry-2x32 (exact JAX semantics) ----------------
__host__ __device__ inline void tf2x32(uint32_t k0, uint32_t k1,
                                       uint32_t x0, uint32_t x1,
                                       uint32_t &o0, uint32_t &o1) {
  const uint32_t k2 = k0 ^ k1 ^ 0x1BD11BDAu;
  x0 += k0; x1 += k1;
#define TFR(r) { x0 += x1; x1 = (x1 << (r)) | (x1 >> (32 - (r))); x1 ^= x0; }
  TFR(13) TFR(15) TFR(26) TFR(6)
  x0 += k1; x1 += k2 + 1u;
  TFR(17) TFR(29) TFR(16) TFR(24)
  x0 += k2; x1 += k0 + 2u;
  TFR(13) TFR(15) TFR(26) TFR(6)
  x0 += k0; x1 += k1 + 3u;
  TFR(17) TFR(29) TFR(16) TFR(24)
  x0 += k1; x1 += k2 + 4u;
  TFR(13) TFR(15) TFR(26) TFR(6)
  x0 += k2; x1 += k0 + 5u;
#undef TFR
  o0 = x0; o1 = x1;
}

__device__ inline void split2048(float v, ushort &h, ushort &l) {
  _Float16 hi = (_Float16)v;
  float r = (v - (float)hi) * 2048.0f;   // scale lo into normal f16 range
  _Float16 lo = (_Float16)r;
  h = __builtin_bit_cast(ushort, hi);
  l = __builtin_bit_cast(ushort, lo);
}

// ------------- K0a: weights -> 32x32x16 A-fragment order, f16 hi/lo (lo x2048) -------------
// frag f = (t*2 + tile)*64 + lane; m = lane&31 -> j = tile*32+m; k-elems:
// ci = 8*(lane>>5) + e. Tap t rotated spatially by r = j&3.
__global__ void k_prep_wfrag(const float* __restrict__ w1,
                             ushort* __restrict__ wfh, ushort* __restrict__ wfl) {
  int idx = blockIdx.x * 256 + threadIdx.x;   // total 49*2*64 = 6272
  if (idx >= NTAP * 2 * 64) return;
  const int lane = idx & 63;
  const int ft = idx >> 6;            // t*2 + tile
  const int t = ft >> 1, tile = ft & 1;
  const int m = lane & 31;
  const int j = tile * 32 + m, co = j >> 2, r = j & 3;
  const int cibase = (lane >> 5) * 8;
  const int ky = t / 7, kx = t - (t / 7) * 7;
  int a = ky, b = kx;
  for (int i = 0; i < r; ++i) { int na = b, nb = 6 - a; a = na; b = nb; }
  PackU ph, pl;
#pragma unroll
  for (int e = 0; e < 8; ++e) {
    const int ci = cibase + e;
    split2048(w1[((co * 16 + ci) * 7 + a) * 7 + b], ph.u[e], pl.u[e]);
  }
  ((uint4*)wfh)[ft * 64 + lane] = ph.v;
  ((uint4*)wfl)[ft * 64 + lane] = pl.v;
}

// ------------- K0b: wsum[o][ci] = 0.25 * sum_t w2[o,ci,t] -------------
__global__ void k_prep_w2(const float* __restrict__ w2, float* __restrict__ wsum) {
  int idx = threadIdx.x;  // 256 = o*16 + ci
  float s = 0.f;
  for (int t = 0; t < 4; ++t) s += w2[idx * 4 + t];
  wsum[idx] = 0.25f * s;
}

// ------------- K1: 7x7 P4 lifting conv via split-f16 32x32x16 MFMA -------------
// 16x16 tile, 256 threads = 4 waves, 2 blocks/CU (launch_bounds(256,2)).
// Wave wid owns cols {4w..4w+3} = 2 groups of 32 px (16 rows x 2 cols).
// Per tap: 4 A-loads (L2, reg-dbuf) + 4 B-loads (LDS, reg-dbuf) + 12 MFMA.
// D mapping (HW-verified m74/m101): col=lane&31 (pixel), row=(reg&3)+8*(reg>>2)+4*(lane>>5) (j).
__global__ __launch_bounds__(256, 2) void k_conv1(
    const float* __restrict__ xsrc,   // NHWC [B,H,W,16]
    const ushort* __restrict__ wfh,   // A-frags hi  [NTAP*2*64] x 16B
    const ushort* __restrict__ wfl,   // A-frags lo (x2048)
    const float* __restrict__ b1,     // [16]
    float* __restrict__ y,            // [NPIX][64]
    float* __restrict__ partials)     // [NBLK][32]
{
  __shared__ __align__(16) ushort xsm[2 * XBUFU];      // 31680 B
  __shared__ float red2[4][32];
  const int tid = threadIdx.x;
  const int lane = tid & 63, wid = tid >> 6;
  const int x0 = blockIdx.x * TILE, y0 = blockIdx.y * TILE;
  const int b = blockIdx.z;
  const int bid = (b * gridDim.y + blockIdx.y) * gridDim.x + blockIdx.x;

  // ---- stage x tile (+halo) as split f16, pixel-major; 16B per thread-item ----
  for (int p = tid; p < XROWS * XCOLS * 2; p += 256) {
    const int half = p & 1, t2 = p >> 1;
    const int lr = t2 / XCOLS, lc = t2 - (t2 / XCOLS) * XCOLS;
    const int gy = y0 + lr - 3, gx = x0 + lc - 3;
    float4 v0, v1;
    if ((unsigned)gy < (unsigned)HH && (unsigned)gx < (unsigned)WW) {
      const float4* px = (const float4*)(xsrc + ((size_t)b * HWSZ + (size_t)gy * WW + gx) * 16 + half * 8);
      v0 = px[0]; v1 = px[1];
    } else {
      v0 = v1 = make_float4(0.f, 0.f, 0.f, 0.f);
    }
    const float xv[8] = {v0.x, v0.y, v0.z, v0.w, v1.x, v1.y, v1.z, v1.w};
    PackU h, l;
#pragma unroll
    for (int c = 0; c < 8; ++c) split2048(xv[c], h.u[c], l.u[c]);
    const int ub = lr * RSU + lc * 16 + half * 8;
    *(uint4*)&xsm[ub] = h.v;
    *(uint4*)&xsm[XBUFU + ub] = l.v;
  }
  __syncthreads();   // the ONLY barrier before epilogue: LDS read-only afterwards

  // ---- per-lane geometry ----
  const int n5 = lane & 31;           // D col = pixel index in group
  const int row = lane & 15;          // pixel row in tile
  const int colof = (lane >> 4) & 1;  // pixel col parity within group
  const int hi5 = lane >> 5;          // k-half (ci 0-7 vs 8-15) and D-row offset
  int bU[2];
#pragma unroll
  for (int g = 0; g < 2; ++g)
    bU[g] = row * RSU + (wid * 4 + 2 * g + colof) * 16 + hi5 * 8;

  const f16x8* __restrict__ WAh = (const f16x8*)wfh;
  const f16x8* __restrict__ WAl = (const f16x8*)wfl;

  // bias per (tile, reg-quad): channel c = tile*8 + hi5 + 2*q2
  float bias[2][4];
#pragma unroll
  for (int tile = 0; tile < 2; ++tile)
#pragma unroll
    for (int q2 = 0; q2 < 4; ++q2) bias[tile][q2] = b1[tile * 8 + hi5 + 2 * q2];

  f32x16 accH[2][2], accC[2][2];   // [group][tile]
#pragma unroll
  for (int g = 0; g < 2; ++g)
#pragma unroll
    for (int tile = 0; tile < 2; ++tile) {
#pragma unroll
      for (int reg = 0; reg < 16; ++reg) {
        accH[g][tile][reg] = bias[tile][reg >> 2];
        accC[g][tile][reg] = 0.f;
      }
    }

  f16x8 Ah[2][2], Al[2][2];   // [buf][tile]
  f16x8 Bh[2][2], Bl[2][2];   // [buf][group]

  // B LDS tap offset
  auto boff = [&](int t) -> int { return (t / 7) * RSU + (t % 7) * 16; };

  // prologue: tap-0 fragments
#pragma unroll
  for (int tile = 0; tile < 2; ++tile) {
    Ah[0][tile] = WAh[tile * 64 + lane];
    Al[0][tile] = WAl[tile * 64 + lane];
  }
#pragma unroll
  for (int g = 0; g < 2; ++g) {
    Bh[0][g] = *(const f16x8*)&xsm[bU[g]];
    Bl[0][g] = *(const f16x8*)&xsm[XBUFU + bU[g]];
  }

#pragma unroll
  for (int t = 0; t < NTAP; ++t) {
    const int cb = t & 1, nb = cb ^ 1;
    if (t < NTAP - 1) {
      // ---- prefetch tap t+1: A from global (L2), B from LDS ----
#pragma unroll
      for (int tile = 0; tile < 2; ++tile) {
        const int f = ((t + 1) * 2 + tile) * 64 + lane;
        Ah[nb][tile] = WAh[f];
        Al[nb][tile] = WAl[f];
      }
      const int off = boff(t + 1);
#pragma unroll
      for (int g = 0; g < 2; ++g) {
        Bh[nb][g] = *(const f16x8*)&xsm[bU[g] + off];
        Bl[nb][g] = *(const f16x8*)&xsm[XBUFU + bU[g] + off];
      }
    }
    __builtin_amdgcn_sched_barrier(0);   // loads pinned above the MFMA cluster
    __builtin_amdgcn_s_setprio(1);
    // 4 independent hh MFMAs
#pragma unroll
    for (int g = 0; g < 2; ++g)
#pragma unroll
      for (int tile = 0; tile < 2; ++tile)
        accH[g][tile] = __builtin_amdgcn_mfma_f32_32x32x16_f16(Ah[cb][tile], Bh[cb][g], accH[g][tile], 0, 0, 0);
    // 4 Ah*Bl, then 4 Al*Bh at dependence distance 4
#pragma unroll
    for (int g = 0; g < 2; ++g)
#pragma unroll
      for (int tile = 0; tile < 2; ++tile)
        accC[g][tile] = __builtin_amdgcn_mfma_f32_32x32x16_f16(Ah[cb][tile], Bl[cb][g], accC[g][tile], 0, 0, 0);
#pragma unroll
    for (int g = 0; g < 2; ++g)
#pragma unroll
      for (int tile = 0; tile < 2; ++tile)
        accC[g][tile] = __builtin_amdgcn_mfma_f32_32x32x16_f16(Al[cb][tile], Bh[cb][g], accC[g][tile], 0, 0, 0);
    __builtin_amdgcn_s_setprio(0);
  }

  // ---- epilogue: combine, store y, BN partials ----
  // D row j = tile*32 + (reg&3) + 8*(reg>>2) + 4*hi5 -> reg-quad q2 stores
  // float4 at j-base = tile*32 + 8*q2 + 4*hi5; channel c = tile*8 + 2*q2 + hi5.
  float sC[2][4], qC[2][4];   // [tile][q2]
#pragma unroll
  for (int tile = 0; tile < 2; ++tile)
#pragma unroll
    for (int q2 = 0; q2 < 4; ++q2) { sC[tile][q2] = 0.f; qC[tile][q2] = 0.f; }

#pragma unroll
  for (int g = 0; g < 2; ++g) {
    const size_t pix = (size_t)b * HWSZ + (size_t)(y0 + row) * WW + (x0 + wid * 4 + 2 * g + colof);
#pragma unroll
    for (int tile = 0; tile < 2; ++tile) {
      f32x16 res;
#pragma unroll
      for (int reg = 0; reg < 16; ++reg)
        res[reg] = accH[g][tile][reg] + accC[g][tile][reg] * 4.8828125e-4f;  // 1/2048
#pragma unroll
      for (int q2 = 0; q2 < 4; ++q2) {
        *(float4*)(y + pix * 64 + tile * 32 + 8 * q2 + 4 * hi5) =
            make_float4(res[4 * q2], res[4 * q2 + 1], res[4 * q2 + 2], res[4 * q2 + 3]);
#pragma unroll
        for (int i = 0; i < 4; ++i) {
          const float v = res[4 * q2 + i];
          sC[tile][q2] += v; qC[tile][q2] += v * v;
        }
      }
    }
  }
  // reduce over the 32 lanes of each hi5 half (xor offsets stay within half)
#pragma unroll
  for (int tile = 0; tile < 2; ++tile)
#pragma unroll
    for (int q2 = 0; q2 < 4; ++q2) {
      float s = sC[tile][q2], q = qC[tile][q2];
#pragma unroll
      for (int off = 1; off <= 16; off <<= 1) {
        s += __shfl_xor(s, off); q += __shfl_xor(q, off);
      }
      if (n5 == 0) {   // lanes 0 (hi5=0: even c) and 32 (hi5=1: odd c)
        const int c = tile * 8 + 2 * q2 + hi5;
        red2[wid][2 * c] = s;
        red2[wid][2 * c + 1] = q;
      }
    }
  __syncthreads();
  if (tid < 32) {
    float v = red2[0][tid] + red2[1][tid] + red2[2][tid] + red2[3][tid];
    partials[(size_t)bid * 32 + tid] = v;
  }
}

// ------------- K2: reduce BN partials -> scale/shift per channel -------------
__global__ __launch_bounds__(256) void k_bnstats(
    const float* __restrict__ partials,  // [NBLK][32]
    const float* __restrict__ gamma, const float* __restrict__ beta,
    float* __restrict__ stats)           // [16][2] = scale, shift
{
  const int c = blockIdx.x;      // 16 blocks
  const int tid = threadIdx.x;   // 256
  float s = 0.f, s2 = 0.f;
  for (int i = tid; i < NBLK; i += 256) {
    s  += partials[(size_t)i * 32 + 2 * c];
    s2 += partials[(size_t)i * 32 + 2 * c + 1];
  }
  __shared__ float rs[256], rs2[256];
  rs[tid] = s; rs2[tid] = s2;
  __syncthreads();
  for (int off = 128; off > 0; off >>= 1) {
    if (tid < off) { rs[tid] += rs[tid + off]; rs2[tid] += rs2[tid + off]; }
    __syncthreads();
  }
  if (tid == 0) {
    const float N = (float)BB * 4.f * HH * WW;  // 1,179,648
    const float mu = rs[0] / N;
    const float var = rs2[0] / N - mu * mu;
    const float rstd = rsqrtf(var + 1e-5f);
    const float sc = gamma[c] * rstd;
    stats[2 * c]     = sc;
    stats[2 * c + 1] = beta[c] - mu * sc;
  }
}

// ------------- K3: BN+relu+orientation-sum+1x1 conv+mask+state update -------------
__global__ __launch_bounds__(256) void k_update(
    const float* __restrict__ xsrc,  // NHWC state (d_in step0, else d_out)
    const float* __restrict__ y,     // [NPIX][64]
    const float* __restrict__ stats, // [16][2]
    const float* __restrict__ wsum,  // [16][16]
    const float* __restrict__ b2,    // [16]
    float* __restrict__ xdst,        // NHWC state out (d_out)
    uint32_t fk0, uint32_t fk1)
{
  __shared__ float sss[32];
  __shared__ float sws[256];
  __shared__ float sb2[16];
  const int tid = threadIdx.x;
  sws[tid] = wsum[tid];
  if (tid < 32) sss[tid] = stats[tid];
  if (tid < 16) sb2[tid] = b2[tid];
  __syncthreads();

  const size_t pix = (size_t)blockIdx.x * 256 + tid;  // < NPIX exactly
  const float4* yp = (const float4*)(y + pix * 64);
  float ysum[16];
#pragma unroll
  for (int c = 0; c < 16; ++c) {
    const float4 v = yp[c];
    const float sc = sss[2 * c], sh = sss[2 * c + 1];
    ysum[c] = fmaxf(fmaf(sc, v.x, sh), 0.f) + fmaxf(fmaf(sc, v.y, sh), 0.f)
            + fmaxf(fmaf(sc, v.z, sh), 0.f) + fmaxf(fmaf(sc, v.w, sh), 0.f);
  }

  // JAX partitionable threefry: bits = h0 ^ h1 of hash(fk, (0, i))
  uint32_t h0, h1;
  tf2x32(fk0, fk1, 0u, (uint32_t)pix, h0, h1);
  const uint32_t bits = h0 ^ h1;
  const float u = __uint_as_float((bits >> 9) | 0x3f800000u) - 1.0f;
  const float m = (u > 0.5f) ? 1.0f : 0.0f;

  const float4* xp = (const float4*)(xsrc + pix * 16);
  float4* op = (float4*)(xdst + pix * 16);
#pragma unroll
  for (int qq = 0; qq < 4; ++qq) {
    const float4 xv = xp[qq];
    float d[4];
#pragma unroll
    for (int jj = 0; jj < 4; ++jj) {
      const int o = 4 * qq + jj;
      float s = sb2[o];
#pragma unroll
      for (int c = 0; c < 16; ++c) s = fmaf(sws[o * 16 + c], ysum[c], s);
      d[jj] = s;
    }
    float4 r;
    r.x = xv.x + d[0] * m;
    r.y = xv.y + d[1] * m;
    r.z = xv.z + d[2] * m;
    r.w = xv.w + d[3] * m;
    if (qq == 0) r.x = xv.x;  // channel 0 clamped to original input
    op[qq] = r;
  }
}

extern "C" void kernel_launch(void* const* d_in, const int* in_sizes, int n_in,
                              void* d_out, int out_size, void* d_ws, size_t ws_size,
                              hipStream_t stream) {
  const float* x_in  = (const float*)d_in[0];
  const float* w1    = (const float*)d_in[1];
  const float* b1    = (const float*)d_in[2];
  const float* gamma = (const float*)d_in[3];
  const float* beta  = (const float*)d_in[4];
  const float* w2    = (const float*)d_in[5];
  const float* b2    = (const float*)d_in[6];
  float* out = (float*)d_out;

  // workspace carve-up: y (75.5 MB) + wfrags + small buffers
  float* ws       = (float*)d_ws;
  float* y        = ws;                                // NPIX*64 floats
  ushort* wfh     = (ushort*)(y + (size_t)NPIX * 64);  // 49*2*64*8 = 50176 ushorts
  ushort* wfl     = wfh + NTAP * 2 * 64 * 8;
  float* wsum     = (float*)(wfl + NTAP * 2 * 64 * 8); // 16B aligned (50176*2*2 B offsets)
  float* partials = wsum + 256;                        // NBLK*32
  float* stats    = partials + NBLK * 32;              // 32

  k_prep_wfrag<<<25, 256, 0, stream>>>(w1, wfh, wfl);
  k_prep_w2<<<1, 256, 0, stream>>>(w2, wsum);

  for (int s = 0; s < NSTEP; ++s) {
    const float* xsrc = (s == 0) ? x_in : out;
    k_conv1<<<dim3(WW / TILE, HH / TILE, BB), 256, 0, stream>>>(xsrc, wfh, wfl, b1, y, partials);
    k_bnstats<<<16, 256, 0, stream>>>(partials, gamma, beta, stats);
    uint32_t fk0, fk1;
    tf2x32(0u, 42u, 0u, (uint32_t)s, fk0, fk1);
    k_update<<<NPIX / 256, 256, 0, stream>>>(xsrc, y, stats, wsum, b2, out, fk0, fk1);
  }
}